// Round 5
// baseline (22080.640 us; speedup 1.0000x reference)
//
#include <hip/hip_runtime.h>
#include <hip/hip_bf16.h>

// =====================================================================
// PlantLSTM R5: weight-resident + LOW-TRAFFIC sync.
//  - R2-R4 post-mortem: all three sync impls identical (~40us/step) ->
//    cost is the POLL STORM (256 lanes/group spinning sc1 loads on 48
//    IC lines), not fence mechanics. Fixes:
//    (1) ONE monotonic counter per group per phase (prep-kernel zeroed,
//        stream-ordered before main). Producers atomic_add once; a
//        SINGLE lane polls cnt >= 16*(t+1) with s_sleep backoff.
//    (2) 2 rendezvous/step (was 3): after h1 gather every WG computes
//        FC1+FC2 for ALL 16 batches redundantly -> pv is local.
//    (3) posts stay sc1 relaxed + s_waitcnt vmcnt(0) ordering.
//  - Weight layout / accum / cells / gathers unchanged from R4.
// =====================================================================

#define TSTEPS 512
#define NIN    32

typedef _Float16 h2 __attribute__((ext_vector_type(2)));
typedef unsigned long long ull;

#if __has_builtin(__builtin_amdgcn_fdot2)
#define FDOT2(a, b, c) __builtin_amdgcn_fdot2((a), (b), (c), false)
#else
#define FDOT2(a, b, c) ((c) + (float)(a).x * (float)(b).x + (float)(a).y * (float)(b).y)
#endif

__device__ __forceinline__ float sigm(float x) { return 1.0f / (1.0f + __expf(-x)); }
__device__ __forceinline__ float tanhf_(float x) {
    float e = __expf(2.0f * x);
    return 1.0f - 2.0f / (e + 1.0f);
}

// ---- workspace layout (bytes) ----
#define W0T_OFF 0u
#define W1T_OFF 606208u
#define F1T_OFF 1654784u      // [128 row][128 k2] h2 = 65536
#define HX0_OFF 2097152u      // [16 g][2 par][16 j][512B]
#define HX1_OFF 2359296u
#define FLG_OFF 2629632u      // [16 g][2 phase] counters, 64B apart
#define WS_NEED 2678784u

#define W0S 592
#define W1S 1040
#define X0S 608
#define X1S 1040

// ------------------------- prep kernels -------------------------
__global__ void prep_w(const float* __restrict__ Wih0, const float* __restrict__ Whh0,
                       const float* __restrict__ Wih1, const float* __restrict__ Whh1,
                       char* __restrict__ ws) {
    int gid = blockIdx.x * 256 + threadIdx.x;
    _Float16* w0 = (_Float16*)(ws + W0T_OFF);
    _Float16* w1 = (_Float16*)(ws + W1T_OFF);
    if (gid < 16 * 64 * 296) {
        int k = gid % 296;
        int rest = gid / 296;
        int rl = rest & 63, j = rest >> 6;
        int row = (rl >> 4) * 256 + j * 16 + (rl & 15);
        float v;
        if (k < 32) v = Wih0[row * 72 + k];                 // x
        else if (k < 288) v = Whh0[row * 256 + (k - 32)];   // h0
        else v = Wih0[row * 72 + 32 + (k - 288)];           // pv
        w0[(j * 64 + rl) * 296 + k] = (_Float16)v;
    } else {
        int gid2 = gid - 16 * 64 * 296;
        if (gid2 < 16 * 64 * 512) {
            int k = gid2 & 511;
            int rest = gid2 >> 9;
            int rl = rest & 63, j = rest >> 6;
            int row = (rl >> 4) * 256 + j * 16 + (rl & 15);
            float v = (k < 256) ? Wih1[row * 256 + k] : Whh1[row * 256 + (k - 256)];
            w1[(j * 64 + rl) * 512 + k] = (_Float16)v;
        }
    }
}

__global__ void prep_fc(const float* __restrict__ fc1w, char* __restrict__ ws) {
    int gid = blockIdx.x * 256 + threadIdx.x;
    _Float16* f1 = (_Float16*)(ws + F1T_OFF);
    if (gid < 16384) {  // [row][k2] h2
        int k2 = gid & 127, r = gid >> 7;
        ((h2*)f1)[gid] = h2{(_Float16)fc1w[r * 256 + 2 * k2],
                           (_Float16)fc1w[r * 256 + 2 * k2 + 1]};
    } else if (gid < 16384 + 512) {
        // zero the rendezvous counters (stream-ordered BEFORE lstm_main;
        // end-of-kernel release writes back L2 so main's IC atomics see 0)
        ((unsigned*)(ws + FLG_OFF))[gid - 16384] = 0u;
    }
}

// ------------------------- sync helpers -------------------------
__device__ __forceinline__ void arrive(unsigned* cnt) {
    asm volatile("s_waitcnt vmcnt(0)" ::: "memory");  // drain data posts first
    __hip_atomic_fetch_add(cnt, 1u, __ATOMIC_RELAXED, __HIP_MEMORY_SCOPE_AGENT);
}
__device__ __forceinline__ void wait_cnt(unsigned* cnt, unsigned tgt) {
    while (__hip_atomic_load(cnt, __ATOMIC_RELAXED, __HIP_MEMORY_SCOPE_AGENT) < tgt)
        __builtin_amdgcn_s_sleep(1);
}
#define CBAR() asm volatile("" ::: "memory")

// ------------------------- gate accumulation -------------------------
__device__ __forceinline__ void accum(const char* __restrict__ w, int WS,
                                      const char* __restrict__ x, int XS,
                                      int c0, int cstep, int cend,
                                      float* g, int lane) {
    float acc[16];
#pragma unroll
    for (int b = 0; b < 16; ++b) acc[b] = 0.0f;
    for (int c = c0; c < cend; c += cstep) {
        float4 wv4 = *(const float4*)(w + lane * WS + c * 16);
        h2 a0 = __builtin_bit_cast(h2, wv4.x), a1 = __builtin_bit_cast(h2, wv4.y);
        h2 a2 = __builtin_bit_cast(h2, wv4.z), a3 = __builtin_bit_cast(h2, wv4.w);
#pragma unroll
        for (int b = 0; b < 16; ++b) {
            float4 xv = *(const float4*)(x + b * XS + c * 16);
            acc[b] = FDOT2(a0, __builtin_bit_cast(h2, xv.x), acc[b]);
            acc[b] = FDOT2(a1, __builtin_bit_cast(h2, xv.y), acc[b]);
            acc[b] = FDOT2(a2, __builtin_bit_cast(h2, xv.z), acc[b]);
            acc[b] = FDOT2(a3, __builtin_bit_cast(h2, xv.w), acc[b]);
        }
    }
#pragma unroll
    for (int b = 0; b < 16; ++b) atomicAdd(&g[b * 64 + lane], acc[b]);
}

// ------------------------- main kernel -------------------------
__global__ __launch_bounds__(512) void lstm_main(
    const float* __restrict__ x_cv, const float* __restrict__ pv_init,
    const int* __restrict__ scen, const float* __restrict__ emb_table,
    const float* __restrict__ Wih0, const float* __restrict__ b_ih0,
    const float* __restrict__ b_hh0, const float* __restrict__ b_ih1,
    const float* __restrict__ b_hh1, const float* __restrict__ fc1_b,
    const float* __restrict__ fc2_w, const float* __restrict__ fc2_b,
    char* __restrict__ ws, float* __restrict__ out) {
    struct __align__(16) SM {
        char w0[64 * W0S];        // 37888
        char w1[64 * W1S];        // 66560
        char xt0[16 * X0S];       // [b][x(32)|h0(256)|pv(8) f16 + pad]
        char xt1[16 * X1S];       // [b][h0(256)|h1(256) f16 + pad]
        float g0[16][64];
        float g1[16][64];
        float biasE[16][64];
        float bias1[64];
        _Float16 htmp[16][16];
        float embs[16][32];
        _Float16 fc1o[16][128];   // relu(fc1) as f16
        int scen_l[16];
    };
    __shared__ SM sm;

    const int tid = threadIdx.x;
    const int lane = tid & 63;
    const int wv = tid >> 6;
    const int bid = blockIdx.x;
    const int g = (bid & 7) * 2 + ((bid >> 3) & 1);
    const int j = bid >> 4;
    const int B0 = g * 16;

    const char* w0g = ws + W0T_OFF + (unsigned)j * (64u * 296u * 2u);
    const char* w1g = ws + W1T_OFF + (unsigned)j * (64u * 512u * 2u);
    ull* hx0 = (ull*)(ws + HX0_OFF) + (unsigned)g * 2u * 16u * 64u;
    ull* hx1 = (ull*)(ws + HX1_OFF) + (unsigned)g * 2u * 16u * 64u;
    unsigned* cnt_h0 = (unsigned*)(ws + FLG_OFF) + (unsigned)g * 32u;       // 64B apart
    unsigned* cnt_h1 = (unsigned*)(ws + FLG_OFF) + (unsigned)g * 32u + 16u;

    // ---- init: scen, embs, zero xt, weights -> LDS ----
    if (tid < 16) sm.scen_l[tid] = scen[B0 + tid];
    __syncthreads();
    {
        int b = tid >> 5, e = tid & 31;
        sm.embs[b][e] = emb_table[sm.scen_l[b] * 32 + e];
    }
    for (int idx = tid; idx < (16 * X0S) / 8; idx += 512) ((ull*)sm.xt0)[idx] = 0ull;
    for (int idx = tid; idx < (16 * X1S) / 8; idx += 512) ((ull*)sm.xt1)[idx] = 0ull;
    for (int idx = tid; idx < 64 * 37; idx += 512) {
        int r = idx / 37, c = idx - r * 37;
        *(float4*)(&sm.w0[r * W0S + c * 16]) = *(const float4*)(w0g + r * 592 + c * 16);
    }
    for (int idx = tid; idx < 64 * 64; idx += 512) {
        int r = idx >> 6, c = idx & 63;
        *(float4*)(&sm.w1[r * W1S + c * 16]) = *(const float4*)(w1g + r * 1024 + c * 16);
    }
    __syncthreads();

    // ---- biases + persistent FC weights ----
    for (int idx = tid; idx < 1024; idx += 512) {
        int b = idx >> 6, rl = idx & 63;
        int row = (rl >> 4) * 256 + j * 16 + (rl & 15);
        float s = b_ih0[row] + b_hh0[row];
        for (int e = 0; e < 32; ++e) s += sm.embs[b][e] * Wih0[row * 72 + 40 + e];
        sm.biasE[b][rl] = s;
    }
    if (tid < 64) {
        int row = (tid >> 4) * 256 + j * 16 + (tid & 15);
        sm.bias1[tid] = b_ih1[row] + b_hh1[row];
    }
    // FC1: thread (ks=tid&3, row=tid>>2): K/4 = 64f = 32 h2 = 8 float4
    const int f_ks = tid & 3;
    const int f_row = tid >> 2;  // 0..127
    float4 f1w[8];
    {
        const char* f1g = ws + F1T_OFF + (unsigned)(f_row * 128 + f_ks * 32) * 4u;
#pragma unroll
        for (int q = 0; q < 8; ++q) f1w[q] = *(const float4*)(f1g + q * 16);
    }
    const float fc1b_r = fc1_b[f_row];
    // FC2: thread (ks2=tid&3, jo=(tid>>2)&7, bo=tid>>5): K/4 = 32f = 16 h2
    const int ks2 = tid & 3, jo = (tid >> 2) & 7, bo = tid >> 5;
    h2 f2wh[16];
#pragma unroll
    for (int q = 0; q < 16; ++q) {
        f2wh[q] = h2{(_Float16)fc2_w[jo * 128 + ks2 * 32 + 2 * q],
                     (_Float16)fc2_w[jo * 128 + ks2 * 32 + 2 * q + 1]};
    }
    const float fc2b_r = fc2_b[jo];
    float c0 = 0.0f, c1 = 0.0f;
    __syncthreads();

    // ---- prologue: gates init, stage x(0) + pv_init ----
    for (int idx = tid; idx < 1024; idx += 512) {
        int b = idx >> 6, rl = idx & 63;
        sm.g0[b][rl] = sm.biasE[b][rl];
        sm.g1[b][rl] = sm.bias1[rl];
    }
    {
        int b = tid >> 5, k = tid & 31;
        float xv = x_cv[((B0 + b) * TSTEPS + 0) * NIN + k];
        *(_Float16*)(&sm.xt0[b * X0S + k * 2]) = (_Float16)xv;
    }
    if (tid < 128) {  // pv_init: 16 b x 8
        int b = tid >> 3, p = tid & 7;
        *(_Float16*)(&sm.xt0[b * X0S + 576 + p * 2]) = (_Float16)pv_init[(B0 + b) * 8 + p];
    }
    __syncthreads();

    // ==================== time loop ====================
    for (int t = 0; t < TSTEPS; ++t) {
        const int par = t & 1;
        const unsigned tgt = 16u * (unsigned)(t + 1);

        // ---- A: L0 gates (x, pv, h0 all local in xt0) ----
        accum(sm.w0, W0S, sm.xt0, X0S, wv, 8, 37, &sm.g0[0][0], lane);
        __syncthreads();  // B1

        // ---- B: cell 0 ----
        if (tid < 256) {
            int ui = tid & 15, b = tid >> 4;
            float gi = sm.g0[b][ui], gf = sm.g0[b][16 + ui];
            float gc = sm.g0[b][32 + ui], go = sm.g0[b][48 + ui];
            c0 = sigm(gf) * c0 + sigm(gi) * tanhf_(gc);
            sm.htmp[b][ui] = (_Float16)(sigm(go) * tanhf_(c0));
        }
        __syncthreads();  // B2

        // ---- C: post h0; L1 h1(t-1)-half; stage x(t+1); g0 re-init; poll ----
        if (wv == 0) {
            ull v = *(const ull*)(&sm.htmp[lane >> 2][(lane & 3) * 4]);
            __hip_atomic_store(&hx0[(par * 16 + j) * 64 + lane], v, __ATOMIC_RELAXED,
                               __HIP_MEMORY_SCOPE_AGENT);
            if (lane == 0) arrive(cnt_h0);
        }
        accum(sm.w1, W1S, sm.xt1, X1S, 32 + wv, 8, 64, &sm.g1[0][0], lane);
        if (t < TSTEPS - 1) {
            int b = tid >> 5, k = tid & 31;
            float xv = x_cv[((B0 + b) * TSTEPS + t + 1) * NIN + k];
            *(_Float16*)(&sm.xt0[b * X0S + k * 2]) = (_Float16)xv;
        }
        for (int idx = tid; idx < 1024; idx += 512) {
            int b = idx >> 6, rl = idx & 63;
            sm.g0[b][rl] = sm.biasE[b][rl];
        }
        if (tid == 0) wait_cnt(cnt_h0, tgt);
        __syncthreads();  // B3
        CBAR();

        // ---- D: gather h0 -> xt1[0:256] & xt0 h0-part ----
        for (int idx = tid; idx < 1024; idx += 512) {
            int jj = idx >> 6, l = idx & 63;
            ull v = __hip_atomic_load(&hx0[(par * 16 + jj) * 64 + l], __ATOMIC_RELAXED,
                                      __HIP_MEMORY_SCOPE_AGENT);
            int b = l >> 2, u = jj * 16 + (l & 3) * 4;
            *(ull*)(&sm.xt1[b * X1S + u * 2]) = v;
            *(ull*)(&sm.xt0[b * X0S + (32 + u) * 2]) = v;
        }
        __syncthreads();  // B4

        // ---- E: L1 h0-half ----
        accum(sm.w1, W1S, sm.xt1, X1S, wv, 8, 32, &sm.g1[0][0], lane);
        __syncthreads();  // B5

        // ---- F: cell 1 ----
        if (tid < 256) {
            int ui = tid & 15, b = tid >> 4;
            float gi = sm.g1[b][ui], gf = sm.g1[b][16 + ui];
            float gc = sm.g1[b][32 + ui], go = sm.g1[b][48 + ui];
            c1 = sigm(gf) * c1 + sigm(gi) * tanhf_(gc);
            sm.htmp[b][ui] = (_Float16)(sigm(go) * tanhf_(c1));
        }
        __syncthreads();  // B6

        // ---- G: post h1; g1 re-init; poll ----
        if (wv == 0) {
            ull v = *(const ull*)(&sm.htmp[lane >> 2][(lane & 3) * 4]);
            __hip_atomic_store(&hx1[(par * 16 + j) * 64 + lane], v, __ATOMIC_RELAXED,
                               __HIP_MEMORY_SCOPE_AGENT);
            if (lane == 0) arrive(cnt_h1);
        }
        for (int idx = tid; idx < 1024; idx += 512) {
            int b = idx >> 6, rl = idx & 63;
            sm.g1[b][rl] = sm.bias1[rl];
        }
        if (tid == 0) wait_cnt(cnt_h1, tgt);
        __syncthreads();  // B7
        CBAR();

        // ---- H: gather h1 -> xt1[256:512] ----
        for (int idx = tid; idx < 1024; idx += 512) {
            int jj = idx >> 6, l = idx & 63;
            ull v = __hip_atomic_load(&hx1[(par * 16 + jj) * 64 + l], __ATOMIC_RELAXED,
                                      __HIP_MEMORY_SCOPE_AGENT);
            int b = l >> 2, u = jj * 16 + (l & 3) * 4;
            *(ull*)(&sm.xt1[b * X1S + (256 + u) * 2]) = v;
        }
        __syncthreads();  // B8

        // ---- I: FC1 for ALL 16 batches (redundant; pv becomes local) ----
        {
#pragma unroll 4
            for (int b = 0; b < 16; ++b) {
                float a = 0.0f;
                const char* xr = &sm.xt1[b * X1S + (256 + f_ks * 64) * 2];
#pragma unroll
                for (int q = 0; q < 8; ++q) {
                    float4 xv = *(const float4*)(xr + q * 16);
                    a = FDOT2(__builtin_bit_cast(h2, f1w[q].x), __builtin_bit_cast(h2, xv.x), a);
                    a = FDOT2(__builtin_bit_cast(h2, f1w[q].y), __builtin_bit_cast(h2, xv.y), a);
                    a = FDOT2(__builtin_bit_cast(h2, f1w[q].z), __builtin_bit_cast(h2, xv.z), a);
                    a = FDOT2(__builtin_bit_cast(h2, f1w[q].w), __builtin_bit_cast(h2, xv.w), a);
                }
                a += __shfl_xor(a, 1);
                a += __shfl_xor(a, 2);
                if (f_ks == 0) sm.fc1o[b][f_row] = (_Float16)fmaxf(a + fc1b_r, 0.0f);
            }
        }
        __syncthreads();  // B9

        // ---- J: FC2 all 16 batches -> own out + local pv ----
        {
            float a = 0.0f;
            const _Float16* xr = &sm.fc1o[bo][ks2 * 32];
#pragma unroll
            for (int q = 0; q < 16; ++q)
                a = FDOT2(f2wh[q], *(const h2*)(xr + 2 * q), a);
            a += __shfl_xor(a, 1);
            a += __shfl_xor(a, 2);
            if (ks2 == 0) {
                float av = a + fc2b_r;
                if (bo == j) out[((B0 + j) * TSTEPS + t) * 8 + jo] = av;
                *(_Float16*)(&sm.xt0[bo * X0S + 576 + jo * 2]) = (_Float16)av;
            }
        }
        __syncthreads();  // B10
    }
}

// ------------------------- launch -------------------------
extern "C" void kernel_launch(void* const* d_in, const int* in_sizes, int n_in,
                              void* d_out, int out_size, void* d_ws, size_t ws_size,
                              hipStream_t stream) {
    if (ws_size < WS_NEED) return;

    const float* x_cv = (const float*)d_in[0];
    const float* pv_init = (const float*)d_in[1];
    const int* scen = (const int*)d_in[2];
    const float* embt = (const float*)d_in[3];
    const float* Wih0 = (const float*)d_in[4];
    const float* Whh0 = (const float*)d_in[5];
    const float* bih0 = (const float*)d_in[6];
    const float* bhh0 = (const float*)d_in[7];
    const float* Wih1 = (const float*)d_in[8];
    const float* Whh1 = (const float*)d_in[9];
    const float* bih1 = (const float*)d_in[10];
    const float* bhh1 = (const float*)d_in[11];
    const float* fc1w = (const float*)d_in[12];
    const float* fc1b = (const float*)d_in[13];
    const float* fc2w = (const float*)d_in[14];
    const float* fc2b = (const float*)d_in[15];

    char* ws = (char*)d_ws;

    prep_w<<<3232, 256, 0, stream>>>(Wih0, Whh0, Wih1, Whh1, ws);
    prep_fc<<<66, 256, 0, stream>>>(fc1w, ws);

    lstm_main<<<256, 512, 0, stream>>>(x_cv, pv_init, scen, embt, Wih0, bih0, bhh0,
                                       bih1, bhh1, fc1b, fc2w, fc2b, ws, (float*)d_out);
}

// Round 6
// 19101.543 us; speedup vs baseline: 1.1560x; 1.1560x over previous
//
#include <hip/hip_runtime.h>
#include <hip/hip_bf16.h>

// =====================================================================
// PlantLSTM R6: REGISTER-resident weights, 4-WG sync groups.
//  - R2-R5 post-mortem: ~40us/step invariant across 4 sync impls ->
//    cost is the 16-participant rendezvous (skew x IC RT), plus LDS
//    read pipe (~10us/step of ds_read for weight streams).
//  - Fix both: group = 4 WGs x 4 batches. All LSTM weights live in
//    VGPRs (204 regs/lane, gate-interleaved float4, static indexing);
//    4 CUs' RFs hold the full 1.72MB. x/h reads are wave-broadcast LDS
//    (trivial). FC1/FC2 weights in LDS (bank-staggered), computed
//    redundantly per WG -> pv local. 2 rendezvous/step (provably
//    minimal for split weights), R5's counter protocol, 4 arrivals.
//  - WG c owns units c*64..c*64+63 (all 4 gates, both layers); wave w
//    owns K-slice w. Lane l <-> unit c*64+l.
// =====================================================================

#define TSTEPS 512

typedef _Float16 h2 __attribute__((ext_vector_type(2)));
typedef unsigned long long ull;

#if __has_builtin(__builtin_amdgcn_fdot2)
#define FDOT2(a, b, c) __builtin_amdgcn_fdot2((a), (b), (c), false)
#else
#define FDOT2(a, b, c) ((c) + (float)(a).x * (float)(b).x + (float)(a).y * (float)(b).y)
#endif
#define BC(x) __builtin_bit_cast(h2, (x))

__device__ __forceinline__ float sigm(float x) { return 1.0f / (1.0f + __expf(-x)); }
__device__ __forceinline__ float tanhf_(float x) {
    float e = __expf(2.0f * x);
    return 1.0f - 2.0f / (e + 1.0f);
}

// ---- ws layout (bytes) ----
// WQT: per-(c,wave,lane) contiguous blobs of 52 float4:
//   q 0..19  : L0, gates {i,f,g,o} as components, K-pair w*20+q of
//              320-col layout [x 32 | h0 256 | pv 8 | zero-pad 24]
//   q 20..35 : L1 h0-cols [w*32 .. +32)
//   q 36..51 : L1 h1-cols [w*32 .. +32)
#define WQT_OFF 0u           // 4c*8w*64l*52q*16B = 1,703,936
#define HXA_OFF 1703936u     // 64g * 2par * 4c * 64 ull = 262,144
#define HXB_OFF 1966080u
#define FLG_OFF 2228224u     // 64g * {cntA, cntB} 64B apart
#define WS_NEED 2244608u

// ------------------------- prep kernel -------------------------
__device__ __forceinline__ float l0col(const float* __restrict__ Wih0,
                                       const float* __restrict__ Whh0, int row, int K) {
    if (K < 32) return Wih0[row * 72 + K];
    if (K < 288) return Whh0[row * 256 + (K - 32)];
    if (K < 296) return Wih0[row * 72 + 32 + (K - 288)];  // pv cols 32..39
    return 0.0f;
}

__global__ void prep_w(const float* __restrict__ Wih0, const float* __restrict__ Whh0,
                       const float* __restrict__ Wih1, const float* __restrict__ Whh1,
                       char* __restrict__ ws) {
    int gid = blockIdx.x * 256 + threadIdx.x;
    if (gid < 106496) {
        int q = gid % 52;
        int rest = gid / 52;
        int l = rest & 63, w = (rest >> 6) & 7, c = rest >> 9;
        float4 v;
        float* vp = (float*)&v;
#pragma unroll
        for (int gg = 0; gg < 4; ++gg) {
            int row = gg * 256 + c * 64 + l;
            float a0, a1;
            if (q < 20) {
                int K = w * 40 + q * 2;
                a0 = l0col(Wih0, Whh0, row, K);
                a1 = l0col(Wih0, Whh0, row, K + 1);
            } else if (q < 36) {
                int K = w * 32 + (q - 20) * 2;
                a0 = Wih1[row * 256 + K];
                a1 = Wih1[row * 256 + K + 1];
            } else {
                int K = w * 32 + (q - 36) * 2;
                a0 = Whh1[row * 256 + K];
                a1 = Whh1[row * 256 + K + 1];
            }
            h2 hv;
            hv.x = (_Float16)a0;
            hv.y = (_Float16)a1;
            vp[gg] = __builtin_bit_cast(float, hv);
        }
        ((float4*)ws)[gid] = v;
    } else {
        int z = gid - 106496;
        if (z < 4096) ((unsigned*)(ws + FLG_OFF))[z] = 0u;  // rendezvous counters
    }
}

// ------------------------- sync helpers (R5, proven) -------------------------
__device__ __forceinline__ void arrive(unsigned* cnt) {
    asm volatile("s_waitcnt vmcnt(0)" ::: "memory");
    __hip_atomic_fetch_add(cnt, 1u, __ATOMIC_RELAXED, __HIP_MEMORY_SCOPE_AGENT);
}
__device__ __forceinline__ void wait_cnt(unsigned* cnt, unsigned tgt) {
    while (__hip_atomic_load(cnt, __ATOMIC_RELAXED, __HIP_MEMORY_SCOPE_AGENT) < tgt)
        __builtin_amdgcn_s_sleep(1);
}
#define CBAR() asm volatile("" ::: "memory")

// ------------------------- MAC helpers -------------------------
__device__ __forceinline__ void mac4(const float4& W, h2 x, float& r0, float& r1,
                                     float& r2, float& r3) {
    r0 = FDOT2(BC(W.x), x, r0);
    r1 = FDOT2(BC(W.y), x, r1);
    r2 = FDOT2(BC(W.z), x, r2);
    r3 = FDOT2(BC(W.w), x, r3);
}
__device__ __forceinline__ float dot8(const float4& W, const float4& X, float s) {
    s = FDOT2(BC(W.x), BC(X.x), s);
    s = FDOT2(BC(W.y), BC(X.y), s);
    s = FDOT2(BC(W.z), BC(X.z), s);
    s = FDOT2(BC(W.w), BC(X.w), s);
    return s;
}

// ------------------------- main kernel -------------------------
__global__ __launch_bounds__(512) void lstm_main(
    const float* __restrict__ x_cv, const float* __restrict__ pv_init,
    const int* __restrict__ scen, const float* __restrict__ emb_table,
    const float* __restrict__ Wih0, const float* __restrict__ b_ih0,
    const float* __restrict__ b_hh0, const float* __restrict__ b_ih1,
    const float* __restrict__ b_hh1, const float* __restrict__ fc1_w,
    const float* __restrict__ fc1_b, const float* __restrict__ fc2_w,
    const float* __restrict__ fc2_b, char* __restrict__ ws,
    float* __restrict__ out) {
    struct __align__(16) SM {
        char fc1w[73856];          // [ks]{stride 18464}[row]{144}[32 h2]
        char fc2w[2048];           // [jo*4+ks][32 f16]
        char xt0[4 * 640];         // [b][x 32 | h0 256 | pv 8 | pad 24] f16
        char xt1[4 * 1024];        // [b][h0 256 | h1 256] f16
        float g0[4][256];          // [b][gate*64 + u]
        float g1[4][256];
        float biasE[4][256];
        float bias1[256];
        unsigned short htmp[4][64];
        char fc1o[4 * 256];        // [b][128 f16]
        float embs[4][32];
        int scen_l[4];
    };
    __shared__ SM sm;

    const int tid = threadIdx.x;
    const int lane = tid & 63;
    const int wv = tid >> 6;
    const int c = blockIdx.x & 3;       // WG index within group
    const int g = blockIdx.x >> 2;      // group
    const int B0 = g * 4;

    ull* hxA = (ull*)(ws + HXA_OFF) + (unsigned)g * 512u;  // [par][c][64]
    ull* hxB = (ull*)(ws + HXB_OFF) + (unsigned)g * 512u;
    unsigned* cntA = (unsigned*)(ws + FLG_OFF) + (unsigned)g * 32u;
    unsigned* cntB = cntA + 16;

    // ---- load weight blob into registers (204 VGPRs, static indexing) ----
    float4 wr[52];
    {
        const float4* wb = (const float4*)(ws + WQT_OFF) +
                           (unsigned)(((c * 8 + wv) * 64 + lane) * 52);
#pragma unroll
        for (int q = 0; q < 52; ++q) wr[q] = wb[q];
    }

    // ---- init I1: scenario ids ----
    if (tid < 4) sm.scen_l[tid] = scen[B0 + tid];
    __syncthreads();

    // ---- init I2: embs, zero xt, FC weights -> LDS, bias1 ----
    if (tid < 128) {
        int b = tid >> 5, e = tid & 31;
        sm.embs[b][e] = emb_table[sm.scen_l[b] * 32 + e];
    }
    if (tid < 320) ((ull*)sm.xt0)[tid] = 0ull;
    ((ull*)sm.xt1)[tid] = 0ull;
    {
        int ks = tid & 3, row = tid >> 2;
        char* dst = sm.fc1w + ks * 18464 + row * 144;
        const float* src = fc1_w + row * 256 + ks * 64;
        for (int e = 0; e < 32; ++e) {
            h2 v;
            v.x = (_Float16)src[2 * e];
            v.y = (_Float16)src[2 * e + 1];
            *(h2*)(dst + e * 4) = v;
        }
    }
    {
        int jo = tid >> 6, ks = (tid >> 4) & 3, e = tid & 15;
        h2 v;
        v.x = (_Float16)fc2_w[jo * 128 + ks * 32 + 2 * e];
        v.y = (_Float16)fc2_w[jo * 128 + ks * 32 + 2 * e + 1];
        *(h2*)(sm.fc2w + (jo * 4 + ks) * 64 + e * 4) = v;
    }
    if (tid < 256) {
        int row = (tid >> 6) * 256 + c * 64 + (tid & 63);
        sm.bias1[tid] = b_ih1[row] + b_hh1[row];
    }
    __syncthreads();

    // ---- init I3: biasE (emb folded), x(0), pv_init ----
    for (int idx = tid; idx < 1024; idx += 512) {
        int b = idx >> 8, r = idx & 255;
        int row = (r >> 6) * 256 + c * 64 + (r & 63);
        float s = b_ih0[row] + b_hh0[row];
        for (int e = 0; e < 32; ++e) s += sm.embs[b][e] * Wih0[row * 72 + 40 + e];
        sm.biasE[b][r] = s;
    }
    if (tid < 128) {
        int b = tid >> 5, k = tid & 31;
        float xv = x_cv[((size_t)(B0 + b) * TSTEPS + 0) * 32 + k];
        *(_Float16*)(sm.xt0 + b * 640 + k * 2) = (_Float16)xv;
    }
    if (tid < 32) {
        int b = tid >> 3, jo = tid & 7;
        *(_Float16*)(sm.xt0 + b * 640 + 576 + jo * 2) = (_Float16)pv_init[(B0 + b) * 8 + jo];
    }
    __syncthreads();

    // ---- init I4: gate buffers <- biases ----
    for (int idx = tid; idx < 1024; idx += 512) {
        int b = idx >> 8, r = idx & 255;
        sm.g0[b][r] = sm.biasE[b][r];
        sm.g1[b][r] = sm.bias1[r];
    }
    const float fc1b_r = fc1_b[tid >> 2];
    const float fc2b_r = (tid < 128) ? fc2_b[(tid >> 2) & 7] : 0.0f;
    float c0 = 0.0f, c1 = 0.0f;
    __syncthreads();

    // ==================== time loop ====================
    for (int t = 0; t < TSTEPS; ++t) {
        const int par = t & 1;
        const unsigned tgt = 4u * (unsigned)(t + 1);

        // ---- P3: L0 gates (register MACs over broadcast x) ----
        {
            float a0[4], a1[4], a2[4], a3[4];
#pragma unroll
            for (int b = 0; b < 4; ++b) a0[b] = a1[b] = a2[b] = a3[b] = 0.0f;
#pragma unroll
            for (int b = 0; b < 4; ++b) {
                const char* xb = sm.xt0 + b * 640 + wv * 80;
#pragma unroll
                for (int q = 0; q < 5; ++q) {
                    float4 xq = *(const float4*)(xb + q * 16);
                    mac4(wr[q * 4 + 0], BC(xq.x), a0[b], a1[b], a2[b], a3[b]);
                    mac4(wr[q * 4 + 1], BC(xq.y), a0[b], a1[b], a2[b], a3[b]);
                    mac4(wr[q * 4 + 2], BC(xq.z), a0[b], a1[b], a2[b], a3[b]);
                    mac4(wr[q * 4 + 3], BC(xq.w), a0[b], a1[b], a2[b], a3[b]);
                }
            }
#pragma unroll
            for (int b = 0; b < 4; ++b) {
                atomicAdd(&sm.g0[b][lane], a0[b]);
                atomicAdd(&sm.g0[b][64 + lane], a1[b]);
                atomicAdd(&sm.g0[b][128 + lane], a2[b]);
                atomicAdd(&sm.g0[b][192 + lane], a3[b]);
            }
        }
        __syncthreads();  // B1: g0 complete

        // ---- P4: cell 0 ----
        if (tid < 256) {
            int u = tid & 63, b = tid >> 6;
            float gi = sm.g0[b][u], gf = sm.g0[b][64 + u];
            float gc = sm.g0[b][128 + u], go = sm.g0[b][192 + u];
            c0 = sigm(gf) * c0 + sigm(gi) * tanhf_(gc);
            float h = sigm(go) * tanhf_(c0);
            sm.htmp[b][u] = __builtin_bit_cast(unsigned short, (_Float16)h);
        }
        __syncthreads();  // B2: htmp ready

        // ---- P5: post h0 + L1 h1(t-1)-half + g0 reinit + wait ----
        float b0a[4], b1a[4], b2a[4], b3a[4];
        if (wv == 0) {
            ull v = *(const ull*)((const char*)sm.htmp +
                                  ((lane >> 4) * 64 + (lane & 15) * 4) * 2);
            __hip_atomic_store(&hxA[(par * 4 + c) * 64 + lane], v, __ATOMIC_RELAXED,
                               __HIP_MEMORY_SCOPE_AGENT);
            if (lane == 0) arrive(cntA);
        }
        {
#pragma unroll
            for (int b = 0; b < 4; ++b) b0a[b] = b1a[b] = b2a[b] = b3a[b] = 0.0f;
#pragma unroll
            for (int b = 0; b < 4; ++b) {
                const char* xb = sm.xt1 + b * 1024 + 512 + wv * 64;
#pragma unroll
                for (int q = 0; q < 4; ++q) {
                    float4 xq = *(const float4*)(xb + q * 16);
                    mac4(wr[36 + q * 4 + 0], BC(xq.x), b0a[b], b1a[b], b2a[b], b3a[b]);
                    mac4(wr[36 + q * 4 + 1], BC(xq.y), b0a[b], b1a[b], b2a[b], b3a[b]);
                    mac4(wr[36 + q * 4 + 2], BC(xq.z), b0a[b], b1a[b], b2a[b], b3a[b]);
                    mac4(wr[36 + q * 4 + 3], BC(xq.w), b0a[b], b1a[b], b2a[b], b3a[b]);
                }
            }
        }
        for (int idx = tid; idx < 1024; idx += 512) {
            int b = idx >> 8, r = idx & 255;
            sm.g0[b][r] = sm.biasE[b][r];
        }
        if (tid == 0) wait_cnt(cntA, tgt);
        __syncthreads();  // B3
        CBAR();

        // ---- P6: gather h0 -> xt1[h0], xt0[h0] ----
        if (tid < 256) {
            int cc = tid >> 6, l = tid & 63;
            ull v = __hip_atomic_load(&hxA[(par * 4 + cc) * 64 + l], __ATOMIC_RELAXED,
                                      __HIP_MEMORY_SCOPE_AGENT);
            int b = l >> 4, ug = cc * 64 + (l & 15) * 4;
            *(ull*)(sm.xt1 + b * 1024 + ug * 2) = v;
            *(ull*)(sm.xt0 + b * 640 + 64 + ug * 2) = v;
        }
        __syncthreads();  // B4

        // ---- P7: L1 h0-half + single atomicAdd of both halves ----
        {
#pragma unroll
            for (int b = 0; b < 4; ++b) {
                const char* xb = sm.xt1 + b * 1024 + wv * 64;
#pragma unroll
                for (int q = 0; q < 4; ++q) {
                    float4 xq = *(const float4*)(xb + q * 16);
                    mac4(wr[20 + q * 4 + 0], BC(xq.x), b0a[b], b1a[b], b2a[b], b3a[b]);
                    mac4(wr[20 + q * 4 + 1], BC(xq.y), b0a[b], b1a[b], b2a[b], b3a[b]);
                    mac4(wr[20 + q * 4 + 2], BC(xq.z), b0a[b], b1a[b], b2a[b], b3a[b]);
                    mac4(wr[20 + q * 4 + 3], BC(xq.w), b0a[b], b1a[b], b2a[b], b3a[b]);
                }
            }
#pragma unroll
            for (int b = 0; b < 4; ++b) {
                atomicAdd(&sm.g1[b][lane], b0a[b]);
                atomicAdd(&sm.g1[b][64 + lane], b1a[b]);
                atomicAdd(&sm.g1[b][128 + lane], b2a[b]);
                atomicAdd(&sm.g1[b][192 + lane], b3a[b]);
            }
        }
        __syncthreads();  // B5: g1 complete

        // ---- P8: cell 1 ----
        if (tid < 256) {
            int u = tid & 63, b = tid >> 6;
            float gi = sm.g1[b][u], gf = sm.g1[b][64 + u];
            float gc = sm.g1[b][128 + u], go = sm.g1[b][192 + u];
            c1 = sigm(gf) * c1 + sigm(gi) * tanhf_(gc);
            float h = sigm(go) * tanhf_(c1);
            sm.htmp[b][u] = __builtin_bit_cast(unsigned short, (_Float16)h);
        }
        __syncthreads();  // B6

        // ---- P9: post h1 + x(t+1) stage + g1 reinit + wait ----
        if (wv == 0) {
            ull v = *(const ull*)((const char*)sm.htmp +
                                  ((lane >> 4) * 64 + (lane & 15) * 4) * 2);
            __hip_atomic_store(&hxB[(par * 4 + c) * 64 + lane], v, __ATOMIC_RELAXED,
                               __HIP_MEMORY_SCOPE_AGENT);
            if (lane == 0) arrive(cntB);
        }
        if (tid >= 128 && tid < 256 && t + 1 < TSTEPS) {
            int tt = tid - 128;
            int b = tt >> 5, k = tt & 31;
            float xv = x_cv[((size_t)(B0 + b) * TSTEPS + t + 1) * 32 + k];
            *(_Float16*)(sm.xt0 + b * 640 + k * 2) = (_Float16)xv;
        }
        for (int idx = tid; idx < 1024; idx += 512) {
            int b = idx >> 8, r = idx & 255;
            sm.g1[b][r] = sm.bias1[r];
        }
        if (tid == 0) wait_cnt(cntB, tgt);
        __syncthreads();  // B7
        CBAR();

        // ---- P10: gather h1 -> xt1[h1] ----
        if (tid < 256) {
            int cc = tid >> 6, l = tid & 63;
            ull v = __hip_atomic_load(&hxB[(par * 4 + cc) * 64 + l], __ATOMIC_RELAXED,
                                      __HIP_MEMORY_SCOPE_AGENT);
            int b = l >> 4, ug = cc * 64 + (l & 15) * 4;
            *(ull*)(sm.xt1 + b * 1024 + 512 + ug * 2) = v;
        }
        __syncthreads();  // B8

        // ---- P1: FC1(t) redundant, all threads (row=tid>>2, ks=tid&3) ----
        {
            const int fks = tid & 3, frow = tid >> 2;
            const char* wbase = sm.fc1w + fks * 18464 + frow * 144;
            float fa[4];
#pragma unroll
            for (int b = 0; b < 4; ++b) fa[b] = 0.0f;
#pragma unroll
            for (int b = 0; b < 4; ++b) {
                const char* xb = sm.xt1 + b * 1024 + 512 + fks * 128;
#pragma unroll
                for (int q = 0; q < 8; ++q) {
                    float4 W = *(const float4*)(wbase + q * 16);
                    float4 X = *(const float4*)(xb + q * 16);
                    fa[b] = dot8(W, X, fa[b]);
                }
            }
#pragma unroll
            for (int b = 0; b < 4; ++b) {
                float s = fa[b];
                s += __shfl_xor(s, 1);
                s += __shfl_xor(s, 2);
                if (fks == 0) {
                    float r = fmaxf(s + fc1b_r, 0.0f);
                    *(unsigned short*)(sm.fc1o + b * 256 + frow * 2) =
                        __builtin_bit_cast(unsigned short, (_Float16)r);
                }
            }
        }
        __syncthreads();  // B9

        // ---- P2: FC2 -> pv (local) + out (WG c==0 writes) ----
        if (tid < 128) {
            int ks = tid & 3, jo = (tid >> 2) & 7, b = tid >> 5;
            const char* wb2 = sm.fc2w + (jo * 4 + ks) * 64;
            const char* xb2 = sm.fc1o + b * 256 + ks * 64;
            float s = 0.0f;
#pragma unroll
            for (int q = 0; q < 4; ++q) {
                float4 W = *(const float4*)(wb2 + q * 16);
                float4 X = *(const float4*)(xb2 + q * 16);
                s = dot8(W, X, s);
            }
            s += __shfl_xor(s, 1);
            s += __shfl_xor(s, 2);
            if (ks == 0) {
                float pv = s + fc2b_r;
                *(_Float16*)(sm.xt0 + b * 640 + 576 + jo * 2) = (_Float16)pv;
                if (c == 0) out[((size_t)(B0 + b) * TSTEPS + t) * 8 + jo] = pv;
            }
        }
        __syncthreads();  // B10 -> next t (L0 reads pv + x(t+1) + h0(t))
    }
}

// ------------------------- launch -------------------------
extern "C" void kernel_launch(void* const* d_in, const int* in_sizes, int n_in,
                              void* d_out, int out_size, void* d_ws, size_t ws_size,
                              hipStream_t stream) {
    if (ws_size < WS_NEED) return;

    const float* x_cv = (const float*)d_in[0];
    const float* pv_init = (const float*)d_in[1];
    const int* scen = (const int*)d_in[2];
    const float* embt = (const float*)d_in[3];
    const float* Wih0 = (const float*)d_in[4];
    const float* Whh0 = (const float*)d_in[5];
    const float* bih0 = (const float*)d_in[6];
    const float* bhh0 = (const float*)d_in[7];
    const float* Wih1 = (const float*)d_in[8];
    const float* Whh1 = (const float*)d_in[9];
    const float* bih1 = (const float*)d_in[10];
    const float* bhh1 = (const float*)d_in[11];
    const float* fc1w = (const float*)d_in[12];
    const float* fc1b = (const float*)d_in[13];
    const float* fc2w = (const float*)d_in[14];
    const float* fc2b = (const float*)d_in[15];

    char* ws = (char*)d_ws;

    prep_w<<<432, 256, 0, stream>>>(Wih0, Whh0, Wih1, Whh1, ws);

    lstm_main<<<256, 512, 0, stream>>>(x_cv, pv_init, scen, embt, Wih0, bih0, bhh0,
                                       bih1, bhh1, fc1w, fc1b, fc2w, fc2b, ws,
                                       (float*)d_out);
}